// Round 2
// baseline (214.734 us; speedup 1.0000x reference)
//
#include <hip/hip_runtime.h>

#define HH 512
#define WD 512
#define HP 514
#define BN 8
#define CN 3

// img_p[b,c,i,j] = noise[b,c,i,j] + (pad(img))[i,j], i,j in [0,514)
__device__ __forceinline__ float imgp_at(const float* __restrict__ img,
                                         const float* __restrict__ noise,
                                         int bc, int i, int j) {
    float v = noise[(bc * HP + i) * HP + j];
    if (i >= 1 && i <= HH && j >= 1 && j <= WD)
        v += img[(bc * HH + (i - 1)) * WD + (j - 1)];
    return v;
}

// Robust per-batch flag read: contract says int32, but hedge for bool bytes.
__device__ __forceinline__ int load_flag(const int* __restrict__ p, int b) {
    bool all01 = true;
#pragma unroll
    for (int i = 0; i < BN; ++i) {
        int v = p[i];
        all01 = all01 && (v == 0 || v == 1);
    }
    if (all01) return p[b];
    const unsigned char* pb = (const unsigned char*)p;
    return pb[b] != 0;
}

// Pass A: img_r[b,h,w] = sum_k(w3[k] * sum_c v_c[k]) / sum_k w3[k]
__global__ __launch_bounds__(256) void pass_a(const float* __restrict__ img,
                                              const float* __restrict__ noise,
                                              float* __restrict__ img_r) {
    int idx = blockIdx.x * blockDim.x + threadIdx.x;
    if (idx >= BN * HH * WD) return;
    int w = idx & (WD - 1);
    int h = (idx >> 9) & (HH - 1);
    int b = idx >> 18;

    float vsum[9], wmin[9];
#pragma unroll
    for (int k = 0; k < 9; ++k) { vsum[k] = 0.f; wmin[k] = 3.4e38f; }

#pragma unroll
    for (int c = 0; c < CN; ++c) {
        int bc = b * CN + c;
        float v[9];
        float s = 0.f;
#pragma unroll
        for (int k = 0; k < 9; ++k) {
            int x = k / 3, y = k % 3;
            v[k] = imgp_at(img, noise, bc, h + x, w + y);
            s += v[k];
        }
        float mean = s * (1.f / 9.f);
        float sd = 0.f;
#pragma unroll
        for (int k = 0; k < 9; ++k) { float d = v[k] - mean; sd += d * d; }
        float inv2v = 4.f / sd;  // 1/(2*var), var = sd/8 (ddof=1)
#pragma unroll
        for (int k = 0; k < 9; ++k) {
            float d = v[k] - mean;
            float wk = __expf(-d * d * inv2v);
            vsum[k] += v[k];
            wmin[k] = fminf(wmin[k], wk);
        }
    }
    float num = 0.f, den = 0.f;
#pragma unroll
    for (int k = 0; k < 9; ++k) { num += vsum[k] * wmin[k]; den += wmin[k]; }
    img_r[idx] = num / den;
}

// Pass B: argmin/argmax over zero-padded img_r window -> recompute w3 at that
// index -> w_mod[b,h,w]
__global__ __launch_bounds__(256) void pass_b(const float* __restrict__ img,
                                              const float* __restrict__ noise,
                                              const float* __restrict__ img_r,
                                              const int* __restrict__ ids_dil,
                                              float* __restrict__ w_mod) {
    int idx = blockIdx.x * blockDim.x + threadIdx.x;
    if (idx >= BN * HH * WD) return;
    int w = idx & (WD - 1);
    int h = (idx >> 9) & (HH - 1);
    int b = idx >> 18;

    float rv[9];
#pragma unroll
    for (int k = 0; k < 9; ++k) {
        int x = k / 3, y = k % 3;
        int i = h + x - 1, j = w + y - 1;
        rv[k] = (i >= 0 && i < HH && j >= 0 && j < WD) ? img_r[(b * HH + i) * WD + j] : 0.f;
    }
    int amin = 0, amax = 0;
    float vmin = rv[0], vmax = rv[0];
#pragma unroll
    for (int k = 1; k < 9; ++k) {
        if (rv[k] < vmin) { vmin = rv[k]; amin = k; }  // first occurrence, like jnp.argmin
        if (rv[k] > vmax) { vmax = rv[k]; amax = k; }
    }
    int ksel = load_flag(ids_dil, b) ? amax : amin;

    float wm = 3.4e38f;
#pragma unroll
    for (int c = 0; c < CN; ++c) {
        int bc = b * CN + c;
        float v[9];
        float s = 0.f;
#pragma unroll
        for (int k = 0; k < 9; ++k) {
            int x = k / 3, y = k % 3;
            v[k] = imgp_at(img, noise, bc, h + x, w + y);
            s += v[k];
        }
        float mean = s * (1.f / 9.f);
        float sd = 0.f;
#pragma unroll
        for (int k = 0; k < 9; ++k) { float d = v[k] - mean; sd += d * d; }
        float d = v[ksel] - mean;
        float wk = __expf(-d * d * (4.f / sd));
        wm = fminf(wm, wk);
    }
    w_mod[idx] = wm;
}

// Pass C: img_mod[b,c,h,w] = sum_k img_e[k]*w_mod_e[k] / sum_k w_mod_e[k];
// out = ids_sel ? img_mod : img, cast to uint8 (wrap) stored as int32.
__global__ __launch_bounds__(256) void pass_c(const float* __restrict__ img,
                                              const float* __restrict__ noise,
                                              const float* __restrict__ w_mod,
                                              const int* __restrict__ ids_sel,
                                              int* __restrict__ out) {
    int idx = blockIdx.x * blockDim.x + threadIdx.x;
    if (idx >= BN * CN * HH * WD) return;
    int w = idx & (WD - 1);
    int h = (idx >> 9) & (HH - 1);
    int t = idx >> 18;  // 0..23
    int b = t / 3, c = t % 3;

    float outv;
    if (!load_flag(ids_sel, b)) {
        outv = img[idx];
    } else {
        int bc = b * CN + c;
        float num = 0.f, den = 0.f;
#pragma unroll
        for (int k = 0; k < 9; ++k) {
            int x = k / 3, y = k % 3;
            int i = h + x - 1, j = w + y - 1;
            float wm = (i >= 0 && i < HH && j >= 0 && j < WD) ? w_mod[(b * HH + i) * WD + j] : 0.f;
            float ve = imgp_at(img, noise, bc, h + x, w + y);
            num += ve * wm;
            den += wm;
        }
        outv = num / den;
    }
    // uint8 cast semantics: trunc toward zero then wrap mod 256 (values in [0, ~256.9))
    out[idx] = ((int)outv) & 255;
}

extern "C" void kernel_launch(void* const* d_in, const int* in_sizes, int n_in,
                              void* d_out, int out_size, void* d_ws, size_t ws_size,
                              hipStream_t stream) {
    const float* img   = (const float*)d_in[0];
    const float* noise = (const float*)d_in[1];
    const int* ids_sel = (const int*)d_in[2];
    const int* ids_dil = (const int*)d_in[3];
    int* out = (int*)d_out;

    float* wsf   = (float*)d_ws;
    float* img_r = wsf;                              // 8*512*512 floats = 8 MB
    float* w_mod = wsf + (size_t)BN * HH * WD;       // 8 MB more

    int n1 = BN * HH * WD;        // 2,097,152
    int n2 = BN * CN * HH * WD;   // 6,291,456
    pass_a<<<(n1 + 255) / 256, 256, 0, stream>>>(img, noise, img_r);
    pass_b<<<(n1 + 255) / 256, 256, 0, stream>>>(img, noise, img_r, ids_dil, w_mod);
    pass_c<<<(n2 + 255) / 256, 256, 0, stream>>>(img, noise, w_mod, ids_sel, out);
}

// Round 3
// 133.073 us; speedup vs baseline: 1.6137x; 1.6137x over previous
//
#include <hip/hip_runtime.h>

#define HH 512
#define WD 512
#define HP 514
#define BN 8
#define CN 3

#define TH 16
#define TW 64

// K1 LDS tile: img_p rows [h0, h0+18), cols [w0, w0+66)
#define K1_ROWS (TH + 2)
#define K1_COLS (TW + 2)
#define K1_PITCH (K1_COLS + 1)  // 67, odd -> no cross-row bank aliasing

// K2 LDS tiles
#define K2_ROWS (TH + 4)          // 20
#define K2_COLS (TW + 4)          // 68
#define K2_PITCH (K2_COLS + 1)    // 69
#define WM_ROWS (TH + 2)          // 18
#define WM_COLS (TW + 2)          // 66
#define WM_PITCH (WM_COLS + 1)    // 67

// Robust per-batch flag read: contract says int32, hedge for bool bytes.
__device__ __forceinline__ int load_flag(const int* __restrict__ p, int b) {
    bool all01 = true;
#pragma unroll
    for (int i = 0; i < BN; ++i) {
        int v = p[i];
        all01 = all01 && (v == 0 || v == 1);
    }
    if (all01) return p[b];
    const unsigned char* pb = (const unsigned char*)p;
    return pb[b] != 0;
}

// K1: img_r[b,h,w] = sum_k(w3[k] * sum_c v_c[k]) / sum_k w3[k], LDS-tiled.
__global__ __launch_bounds__(256) void k1(const float* __restrict__ img,
                                          const float* __restrict__ noise,
                                          const int* __restrict__ ids_sel,
                                          float* __restrict__ img_r) {
    int b = blockIdx.z;
    if (!load_flag(ids_sel, b)) return;  // img_r unused for unselected batches
    int h0 = blockIdx.y * TH, w0 = blockIdx.x * TW;
    int t = threadIdx.x;

    __shared__ float sp[CN][K1_ROWS * K1_PITCH];

#pragma unroll
    for (int c = 0; c < CN; ++c) {
        const float* nz = noise + (size_t)(b * CN + c) * HP * HP;
        const float* im = img + (size_t)(b * CN + c) * HH * WD;
        for (int idx = t; idx < K1_ROWS * K1_COLS; idx += 256) {
            int r = idx / K1_COLS, cc = idx - r * K1_COLS;
            int ip = h0 + r, jp = w0 + cc;  // img_p coords, always in [0,514)
            float v = nz[ip * HP + jp];
            if (ip >= 1 && ip <= HH && jp >= 1 && jp <= WD)
                v += im[(ip - 1) * WD + (jp - 1)];
            sp[c][r * K1_PITCH + cc] = v;
        }
    }
    __syncthreads();

    int tx = t & 63, ty = t >> 6;  // ty in 0..3
#pragma unroll
    for (int rr = 0; rr < 4; ++rr) {
        int ly = ty * 4 + rr;  // 0..15, wave-uniform
        float vsum[9], wmin[9];
#pragma unroll
        for (int k = 0; k < 9; ++k) { vsum[k] = 0.f; wmin[k] = 3.4e38f; }
#pragma unroll
        for (int c = 0; c < CN; ++c) {
            float v[9], s = 0.f;
#pragma unroll
            for (int k = 0; k < 9; ++k) {
                int x = k / 3, y = k % 3;
                v[k] = sp[c][(ly + x) * K1_PITCH + tx + y];
                s += v[k];
            }
            float mean = s * (1.f / 9.f);
            float sd = 0.f;
#pragma unroll
            for (int k = 0; k < 9; ++k) { float d = v[k] - mean; sd += d * d; }
            float inv2v = 4.f / sd;  // 1/(2*var), var = sd/8 (ddof=1)
#pragma unroll
            for (int k = 0; k < 9; ++k) {
                float d = v[k] - mean;
                float wk = __expf(-d * d * inv2v);
                vsum[k] += v[k];
                wmin[k] = fminf(wmin[k], wk);
            }
        }
        float num = 0.f, den = 0.f;
#pragma unroll
        for (int k = 0; k < 9; ++k) { num += vsum[k] * wmin[k]; den += wmin[k]; }
        img_r[((size_t)b * HH + h0 + ly) * WD + w0 + tx] = num / den;
    }
}

// K2: fused pass B + C. Computes w_mod for the (TH+2)x(TW+2) halo in LDS,
// then the final weighted average + uint8-wrap store.
__global__ __launch_bounds__(256) void k2(const float* __restrict__ img,
                                          const float* __restrict__ noise,
                                          const float* __restrict__ img_r,
                                          const int* __restrict__ ids_sel,
                                          const int* __restrict__ ids_dil,
                                          int* __restrict__ out) {
    int b = blockIdx.z;
    int h0 = blockIdx.y * TH, w0 = blockIdx.x * TW;
    int t = threadIdx.x;
    int tx = t & 63, ty = t >> 6;

    if (!load_flag(ids_sel, b)) {  // uniform per block: plain uint8 copy
#pragma unroll
        for (int c = 0; c < CN; ++c) {
            const float* im = img + (size_t)(b * CN + c) * HH * WD;
            int* op = out + (size_t)(b * CN + c) * HH * WD;
#pragma unroll
            for (int rr = 0; rr < 4; ++rr) {
                int ly = ty * 4 + rr;
                op[(h0 + ly) * WD + w0 + tx] = ((int)im[(h0 + ly) * WD + w0 + tx]) & 255;
            }
        }
        return;
    }
    bool dil = load_flag(ids_dil, b) != 0;

    __shared__ float sp[CN][K2_ROWS * K2_PITCH];
    __shared__ float sr[K2_ROWS * K2_PITCH];
    __shared__ float swm[WM_ROWS * WM_PITCH];

    // Stage img_p rows [h0-1, h0+19), cols [w0-1, w0+67) (index-clamped; the
    // clamped entries only feed out-of-image w_mod pixels, which are forced 0).
#pragma unroll
    for (int c = 0; c < CN; ++c) {
        const float* nz = noise + (size_t)(b * CN + c) * HP * HP;
        const float* im = img + (size_t)(b * CN + c) * HH * WD;
        for (int idx = t; idx < K2_ROWS * K2_COLS; idx += 256) {
            int r = idx / K2_COLS, cc = idx - r * K2_COLS;
            int ip = h0 - 1 + r, jp = w0 - 1 + cc;
            ip = ip < 0 ? 0 : (ip > HP - 1 ? HP - 1 : ip);
            jp = jp < 0 ? 0 : (jp > HP - 1 ? HP - 1 : jp);
            float v = nz[ip * HP + jp];
            if (ip >= 1 && ip <= HH && jp >= 1 && jp <= WD)
                v += im[(ip - 1) * WD + (jp - 1)];
            sp[c][r * K2_PITCH + cc] = v;
        }
    }
    // Stage img_r rows [h0-2, h0+18), cols [w0-2, w0+66), zero-padded.
    for (int idx = t; idx < K2_ROWS * K2_COLS; idx += 256) {
        int r = idx / K2_COLS, cc = idx - r * K2_COLS;
        int i = h0 - 2 + r, j = w0 - 2 + cc;
        sr[r * K2_PITCH + cc] =
            (i >= 0 && i < HH && j >= 0 && j < WD) ? img_r[((size_t)b * HH + i) * WD + j] : 0.f;
    }
    __syncthreads();

    // Phase 2: w_mod for pixels rows [h0-1, h0+17), cols [w0-1, w0+65).
    for (int idx = t; idx < WM_ROWS * WM_COLS; idx += 256) {
        int r = idx / WM_COLS, cc = idx - r * WM_COLS;
        int h = h0 - 1 + r, w = w0 - 1 + cc;
        float wmv = 0.f;
        if (h >= 0 && h < HH && w >= 0 && w < WD) {
            // img_r window: sr local rows r..r+2, cols cc..cc+2
            float rv[9];
#pragma unroll
            for (int k = 0; k < 9; ++k) {
                int x = k / 3, y = k % 3;
                rv[k] = sr[(r + x) * K2_PITCH + cc + y];
            }
            int amin = 0, amax = 0;
            float vmin = rv[0], vmax = rv[0];
#pragma unroll
            for (int k = 1; k < 9; ++k) {
                if (rv[k] < vmin) { vmin = rv[k]; amin = k; }  // first occurrence
                if (rv[k] > vmax) { vmax = rv[k]; amax = k; }
            }
            int ksel = dil ? amax : amin;
            float wm = 3.4e38f;
#pragma unroll
            for (int c = 0; c < CN; ++c) {
                float v[9], s = 0.f;
#pragma unroll
                for (int k = 0; k < 9; ++k) {
                    int x = k / 3, y = k % 3;
                    v[k] = sp[c][(r + x) * K2_PITCH + cc + y];
                    s += v[k];
                }
                float mean = s * (1.f / 9.f);
                float sd = 0.f;
#pragma unroll
                for (int k = 0; k < 9; ++k) { float d = v[k] - mean; sd += d * d; }
                float d = v[ksel] - mean;
                wm = fminf(wm, __expf(-d * d * (4.f / sd)));
            }
            wmv = wm;
        }
        swm[r * WM_PITCH + cc] = wmv;
    }
    __syncthreads();

    // Phase 3: final weighted average per pixel, 3 channels.
#pragma unroll
    for (int rr = 0; rr < 4; ++rr) {
        int ly = ty * 4 + rr;
        float wmv[9], den = 0.f;
#pragma unroll
        for (int k = 0; k < 9; ++k) {
            int x = k / 3, y = k % 3;
            wmv[k] = swm[(ly + x) * WM_PITCH + tx + y];
            den += wmv[k];
        }
        float rden = 1.f / den;
#pragma unroll
        for (int c = 0; c < CN; ++c) {
            float num = 0.f;
#pragma unroll
            for (int k = 0; k < 9; ++k) {
                int x = k / 3, y = k % 3;
                num += sp[c][(ly + 1 + x) * K2_PITCH + tx + 1 + y] * wmv[k];
            }
            out[((size_t)(b * CN + c) * HH + h0 + ly) * WD + w0 + tx] = ((int)(num * rden)) & 255;
        }
    }
}

extern "C" void kernel_launch(void* const* d_in, const int* in_sizes, int n_in,
                              void* d_out, int out_size, void* d_ws, size_t ws_size,
                              hipStream_t stream) {
    const float* img   = (const float*)d_in[0];
    const float* noise = (const float*)d_in[1];
    const int* ids_sel = (const int*)d_in[2];
    const int* ids_dil = (const int*)d_in[3];
    int* out = (int*)d_out;

    float* img_r = (float*)d_ws;  // 8*512*512 floats = 8 MB

    dim3 grid(WD / TW, HH / TH, BN);  // 8 x 32 x 8
    k1<<<grid, 256, 0, stream>>>(img, noise, ids_sel, img_r);
    k2<<<grid, 256, 0, stream>>>(img, noise, img_r, ids_sel, ids_dil, out);
}

// Round 4
// 130.674 us; speedup vs baseline: 1.6433x; 1.0184x over previous
//
#include <hip/hip_runtime.h>

#define HH 512
#define WD 512
#define HP 514
#define BN 8
#define CN 3

#define TH 16
#define TW 64

// Fused-kernel LDS tiles (all odd pitches -> no power-of-2 bank aliasing)
#define SP_ROWS (TH + 6)          // 22  img_p rows [h0-2, h0+20)
#define SP_COLS (TW + 6)          // 70  img_p cols [w0-2, w0+68)
#define SP_PITCH (SP_COLS + 1)    // 71
#define SR_ROWS (TH + 4)          // 20  img_r rows [h0-2, h0+18)
#define SR_COLS (TW + 4)          // 68
#define SR_PITCH (SR_COLS + 1)    // 69
#define WM_ROWS (TH + 2)          // 18  w_mod rows [h0-1, h0+17)
#define WM_COLS (TW + 2)          // 66
#define WM_PITCH (WM_COLS + 1)    // 67

// Robust per-batch flag read: contract says int32, hedge for bool bytes.
__device__ __forceinline__ int load_flag(const int* __restrict__ p, int b) {
    bool all01 = true;
#pragma unroll
    for (int i = 0; i < BN; ++i) {
        int v = p[i];
        all01 = all01 && (v == 0 || v == 1);
    }
    if (all01) return p[b];
    const unsigned char* pb = (const unsigned char*)p;
    return pb[b] != 0;
}

// One fused kernel: stage img_p -> img_r halo -> w_mod halo -> final average.
__global__ __launch_bounds__(256) void fused(const float* __restrict__ img,
                                             const float* __restrict__ noise,
                                             const int* __restrict__ ids_sel,
                                             const int* __restrict__ ids_dil,
                                             int* __restrict__ out) {
    int b = blockIdx.z;
    int h0 = blockIdx.y * TH, w0 = blockIdx.x * TW;
    int t = threadIdx.x;
    int tx = t & 63, ty = t >> 6;

    if (!load_flag(ids_sel, b)) {  // uniform per block: plain uint8 copy
#pragma unroll
        for (int c = 0; c < CN; ++c) {
            const float* im = img + (size_t)(b * CN + c) * HH * WD;
            int* op = out + (size_t)(b * CN + c) * HH * WD;
#pragma unroll
            for (int rr = 0; rr < 4; ++rr) {
                int ly = ty * 4 + rr;
                op[(h0 + ly) * WD + w0 + tx] = ((int)im[(h0 + ly) * WD + w0 + tx]) & 255;
            }
        }
        return;
    }
    bool dil = load_flag(ids_dil, b) != 0;

    __shared__ float sp[CN][SP_ROWS * SP_PITCH];  // img_p tile (3 ch)
    __shared__ float sr[SR_ROWS * SR_PITCH];      // img_r halo (zero-padded)
    __shared__ float swm[WM_ROWS * WM_PITCH];     // w_mod halo (zero-padded)

    // Phase 1: stage img_p rows [h0-2, h0+20), cols [w0-2, w0+68), clamped.
    // Clamped entries feed only out-of-image img_r/w_mod pixels (forced 0).
#pragma unroll
    for (int c = 0; c < CN; ++c) {
        const float* nz = noise + (size_t)(b * CN + c) * HP * HP;
        const float* im = img + (size_t)(b * CN + c) * HH * WD;
        for (int idx = t; idx < SP_ROWS * SP_COLS; idx += 256) {
            int r = idx / SP_COLS, cc = idx - r * SP_COLS;
            int ip = h0 - 2 + r, jp = w0 - 2 + cc;
            ip = ip < 0 ? 0 : (ip > HP - 1 ? HP - 1 : ip);
            jp = jp < 0 ? 0 : (jp > HP - 1 ? HP - 1 : jp);
            float v = nz[ip * HP + jp];
            if (ip >= 1 && ip <= HH && jp >= 1 && jp <= WD)
                v += im[(ip - 1) * WD + (jp - 1)];
            sp[c][r * SP_PITCH + cc] = v;
        }
    }
    __syncthreads();

    // Phase 2: img_r for pixel rows [h0-2, h0+18), cols [w0-2, w0+66).
    // Pixel (h0-2+r, w0-2+cc) windows sp rows r..r+2, cols cc..cc+2.
    for (int idx = t; idx < SR_ROWS * SR_COLS; idx += 256) {
        int r = idx / SR_COLS, cc = idx - r * SR_COLS;
        int h = h0 - 2 + r, w = w0 - 2 + cc;
        float val = 0.f;
        if (h >= 0 && h < HH && w >= 0 && w < WD) {
            float vsum[9], wmin[9];
#pragma unroll
            for (int k = 0; k < 9; ++k) { vsum[k] = 0.f; wmin[k] = 3.4e38f; }
#pragma unroll
            for (int c = 0; c < CN; ++c) {
                float v[9], s = 0.f;
#pragma unroll
                for (int k = 0; k < 9; ++k) {
                    int x = k / 3, y = k % 3;
                    v[k] = sp[c][(r + x) * SP_PITCH + cc + y];
                    s += v[k];
                }
                float mean = s * (1.f / 9.f);
                float sd = 0.f;
#pragma unroll
                for (int k = 0; k < 9; ++k) { float d = v[k] - mean; sd += d * d; }
                float inv2v = 4.f / sd;  // 1/(2*var), var = sd/8 (ddof=1)
#pragma unroll
                for (int k = 0; k < 9; ++k) {
                    float d = v[k] - mean;
                    float wk = __expf(-d * d * inv2v);
                    vsum[k] += v[k];
                    wmin[k] = fminf(wmin[k], wk);
                }
            }
            float num = 0.f, den = 0.f;
#pragma unroll
            for (int k = 0; k < 9; ++k) { num += vsum[k] * wmin[k]; den += wmin[k]; }
            val = num / den;
        }
        sr[r * SR_PITCH + cc] = val;
    }
    __syncthreads();

    // Phase 3: w_mod for pixel rows [h0-1, h0+17), cols [w0-1, w0+65).
    // Pixel (h0-1+r, w0-1+cc): img_r window sr rows r..r+2; img_p window
    // sp rows r+1..r+3, cols cc+1..cc+3.
    for (int idx = t; idx < WM_ROWS * WM_COLS; idx += 256) {
        int r = idx / WM_COLS, cc = idx - r * WM_COLS;
        int h = h0 - 1 + r, w = w0 - 1 + cc;
        float wmv = 0.f;
        if (h >= 0 && h < HH && w >= 0 && w < WD) {
            float rv[9];
#pragma unroll
            for (int k = 0; k < 9; ++k) {
                int x = k / 3, y = k % 3;
                rv[k] = sr[(r + x) * SR_PITCH + cc + y];
            }
            int amin = 0, amax = 0;
            float vmin = rv[0], vmax = rv[0];
#pragma unroll
            for (int k = 1; k < 9; ++k) {
                if (rv[k] < vmin) { vmin = rv[k]; amin = k; }  // first occurrence
                if (rv[k] > vmax) { vmax = rv[k]; amax = k; }
            }
            int ksel = dil ? amax : amin;
            float wm = 3.4e38f;
#pragma unroll
            for (int c = 0; c < CN; ++c) {
                float v[9], s = 0.f;
#pragma unroll
                for (int k = 0; k < 9; ++k) {
                    int x = k / 3, y = k % 3;
                    v[k] = sp[c][(r + 1 + x) * SP_PITCH + cc + 1 + y];
                    s += v[k];
                }
                float mean = s * (1.f / 9.f);
                float sd = 0.f;
#pragma unroll
                for (int k = 0; k < 9; ++k) { float d = v[k] - mean; sd += d * d; }
                float d = v[ksel] - mean;
                wm = fminf(wm, __expf(-d * d * (4.f / sd)));
            }
            wmv = wm;
        }
        swm[r * WM_PITCH + cc] = wmv;
    }
    __syncthreads();

    // Phase 4: final weighted average per output pixel, 3 channels.
    // Output (h0+ly, w0+tx): swm rows ly..ly+2, cols tx..tx+2; img_p window
    // sp rows ly+2..ly+4, cols tx+2..tx+4.
#pragma unroll
    for (int rr = 0; rr < 4; ++rr) {
        int ly = ty * 4 + rr;
        float wmv[9], den = 0.f;
#pragma unroll
        for (int k = 0; k < 9; ++k) {
            int x = k / 3, y = k % 3;
            wmv[k] = swm[(ly + x) * WM_PITCH + tx + y];
            den += wmv[k];
        }
        float rden = 1.f / den;
#pragma unroll
        for (int c = 0; c < CN; ++c) {
            float num = 0.f;
#pragma unroll
            for (int k = 0; k < 9; ++k) {
                int x = k / 3, y = k % 3;
                num += sp[c][(ly + 2 + x) * SP_PITCH + tx + 2 + y] * wmv[k];
            }
            out[((size_t)(b * CN + c) * HH + h0 + ly) * WD + w0 + tx] = ((int)(num * rden)) & 255;
        }
    }
}

extern "C" void kernel_launch(void* const* d_in, const int* in_sizes, int n_in,
                              void* d_out, int out_size, void* d_ws, size_t ws_size,
                              hipStream_t stream) {
    const float* img   = (const float*)d_in[0];
    const float* noise = (const float*)d_in[1];
    const int* ids_sel = (const int*)d_in[2];
    const int* ids_dil = (const int*)d_in[3];
    int* out = (int*)d_out;

    dim3 grid(WD / TW, HH / TH, BN);  // 8 x 32 x 8 = 2048 blocks
    fused<<<grid, 256, 0, stream>>>(img, noise, ids_sel, ids_dil, out);
}